// Round 2
// baseline (559.564 us; speedup 1.0000x reference)
//
#include <hip/hip_runtime.h>

// MaxUnpooling2D scatter-add.
// Input:  (8,128,128,64) f32, indices int32 in [0, 256*256*64)
// Output: (8,256,256,64) f32, zero-initialized, out[b, idx&~63 | c] += v
//
// Decode simplification (out_c == C == 64):
//   y*(out_w*out_c) + x*out_c + f == (idx & ~63) + c
// where c = input channel (reference substitutes channel pos for idx%64).

constexpr int IN_PER_B_LOG2  = 20;  // 128*128*64 = 2^20
constexpr int OUT_PER_B_LOG2 = 22;  // 256*256*64 = 2^22
constexpr long long N = 8LL << IN_PER_B_LOG2;  // 8,388,608 input elements

// Zero-fill with float4 stores: 134 MB at ~4.5+ TB/s ≈ 30 us
// (hipMemsetAsync measured ~150 us for the same).
__global__ __launch_bounds__(256) void zero_out(float4* __restrict__ out)
{
    int t = blockIdx.x * blockDim.x + threadIdx.x;
    out[t] = float4{0.f, 0.f, 0.f, 0.f};
}

__global__ __launch_bounds__(256) void unpool_scatter(
    const float* __restrict__ in,
    const int*   __restrict__ idx,
    float*       __restrict__ out)
{
    int t = blockIdx.x * blockDim.x + threadIdx.x;   // one thread = 4 elements
    float4 v  = reinterpret_cast<const float4*>(in)[t];
    int4   i4 = reinterpret_cast<const int4*>(idx)[t];
    int e0 = t << 2;

    int b = e0 >> IN_PER_B_LOG2;           // same for all 4 (C=64 divides 4-groups)
    int c0 = e0 & 63;                      // channels c0..c0+3, same spatial loc
    int out_b = b << OUT_PER_B_LOG2;

    // unsafeAtomicAdd -> native global_atomic_add_f32 (no CAS loop, no return).
    // Duplicate (b,p,c) targets still sum correctly; device scope covers XCDs.
    unsafeAtomicAdd(out + (out_b | (i4.x & ~63) | (c0 + 0)), v.x);
    unsafeAtomicAdd(out + (out_b | (i4.y & ~63) | (c0 + 1)), v.y);
    unsafeAtomicAdd(out + (out_b | (i4.z & ~63) | (c0 + 2)), v.z);
    unsafeAtomicAdd(out + (out_b | (i4.w & ~63) | (c0 + 3)), v.w);
}

extern "C" void kernel_launch(void* const* d_in, const int* in_sizes, int n_in,
                              void* d_out, int out_size, void* d_ws, size_t ws_size,
                              hipStream_t stream)
{
    const float* in  = (const float*)d_in[0];
    const int*   idx = (const int*)d_in[1];
    float*       out = (float*)d_out;

    // Harness poisons d_out with 0xAA before every call; reference starts from zeros.
    const int threads = 256;
    {
        int n_vec4 = out_size / 4;                   // 8,388,608 float4 stores
        zero_out<<<n_vec4 / threads, threads, 0, stream>>>((float4*)out);
    }

    const int n_thr = (int)(N / 4);                  // 2,097,152 threads
    unpool_scatter<<<n_thr / threads, threads, 0, stream>>>(in, idx, out);
}

// Round 3
// 261.995 us; speedup vs baseline: 2.1358x; 2.1358x over previous
//
#include <hip/hip_runtime.h>
#include <stdint.h>

// MaxUnpooling2D scatter-add, two-phase (bin by output tile, then reduce).
//
// Target word: w = (batch << 22) | (idx & ~63) | c   (25-bit, see decode note)
//   decode: out_c == C == 64  =>  y*out_w*out_c + x*out_c + f == (idx&~63) + c
//
// Phase 1: 1024 blocks x 8192 elems; LDS counting sort by bin = w>>14 (2048
//   bins); write per-block segment (coalesced) + per-(block,bin) start table.
// Phase 2: 2048 blocks (one per bin); gather slices from all 1024 segments,
//   accumulate in 64 KB LDS tile (ds_add_f32), store the full 16384-word
//   output tile with plain coalesced stores. No zero pass, no global atomics.

constexpr int  BINS            = 2048;
constexpr int  P1_BLOCKS       = 1024;
constexpr int  ELEMS_PER_BLOCK = 8192;       // elements binned per p1 block
constexpr int  WORDS_PER_BIN   = 1 << 14;    // 16384 output words per bin
constexpr int  IN_PER_B_LOG2   = 20;         // 128*128*64 = 2^20
constexpr int  OUT_PER_B_LOG2  = 22;         // 256*256*64 = 2^22
constexpr long long N = 8LL << IN_PER_B_LOG2;            // 8,388,608
constexpr size_t SEG_BYTES   = (size_t)P1_BLOCKS * ELEMS_PER_BLOCK * 8; // 67.1 MB
constexpr size_t TABLE_BYTES = (size_t)P1_BLOCKS * BINS * 4;            // 8.4 MB
constexpr size_t WS_NEEDED   = SEG_BYTES + TABLE_BYTES;                 // 75.5 MB

__global__ __launch_bounds__(256) void p1_bin(
    const float4* __restrict__ in4, const int4* __restrict__ idx4,
    uint2* __restrict__ seg, uint32_t* __restrict__ table)
{
    __shared__ uint32_t hist[BINS];               // counts -> starts -> cursor
    __shared__ uint32_t scan_tmp[256];
    __shared__ uint2    staging[ELEMS_PER_BLOCK]; // 64 KB
    const int blk = blockIdx.x, t = threadIdx.x;

    #pragma unroll
    for (int j = 0; j < BINS / 256; ++j) hist[t + j * 256] = 0;
    __syncthreads();

    float4 v[8]; int4 ix[8];
    const int base4 = blk * (ELEMS_PER_BLOCK / 4);   // float4 index base
    #pragma unroll
    for (int j = 0; j < 8; ++j) {
        v[j]  = in4 [base4 + j * 256 + t];
        ix[j] = idx4[base4 + j * 256 + t];
    }

    // histogram over bins
    #pragma unroll
    for (int j = 0; j < 8; ++j) {
        const int e0 = (base4 + j * 256 + t) * 4;       // flat input elem idx
        const uint32_t hi = (uint32_t)(e0 >> IN_PER_B_LOG2) << OUT_PER_B_LOG2;
        const int c0 = e0 & 63;
        const int* ip = &ix[j].x;
        #pragma unroll
        for (int l = 0; l < 4; ++l) {
            uint32_t w = hi | ((uint32_t)ip[l] & ~63u) | (uint32_t)(c0 + l);
            atomicAdd(&hist[w >> 14], 1u);
        }
    }
    __syncthreads();

    // block-wide exclusive scan of hist -> starts (in place), record to table
    uint32_t c8[8], local = 0;
    #pragma unroll
    for (int j = 0; j < 8; ++j) { c8[j] = hist[t * 8 + j]; local += c8[j]; }
    scan_tmp[t] = local;
    __syncthreads();
    for (int off = 1; off < 256; off <<= 1) {
        uint32_t x = (t >= off) ? scan_tmp[t - off] : 0;
        __syncthreads();
        scan_tmp[t] += x;
        __syncthreads();
    }
    uint32_t run = scan_tmp[t] - local;      // exclusive prefix for this thread
    uint32_t st[8];
    #pragma unroll
    for (int j = 0; j < 8; ++j) { st[j] = run; run += c8[j]; }
    #pragma unroll
    for (int j = 0; j < 8; ++j) hist[t * 8 + j] = st[j];    // cursor
    // per-(block,bin) start table; 2x dwordx4 per thread
    {
        uint4* t4 = (uint4*)(table + (size_t)blk * BINS);
        t4[t * 2 + 0] = uint4{st[0], st[1], st[2], st[3]};
        t4[t * 2 + 1] = uint4{st[4], st[5], st[6], st[7]};
    }
    __syncthreads();

    // counting-sort scatter into LDS staging
    #pragma unroll
    for (int j = 0; j < 8; ++j) {
        const int e0 = (base4 + j * 256 + t) * 4;
        const uint32_t hi = (uint32_t)(e0 >> IN_PER_B_LOG2) << OUT_PER_B_LOG2;
        const int c0 = e0 & 63;
        const int*   ip = &ix[j].x;
        const float* vp = &v[j].x;
        #pragma unroll
        for (int l = 0; l < 4; ++l) {
            uint32_t w = hi | ((uint32_t)ip[l] & ~63u) | (uint32_t)(c0 + l);
            uint32_t pos = atomicAdd(&hist[w >> 14], 1u);
            staging[pos] = uint2{w & 0x3FFFu, __float_as_uint(vp[l])};
        }
    }
    __syncthreads();

    // coalesced dump: 64 KB staging -> global segment
    const uint4* s4 = (const uint4*)staging;
    uint4* g4 = (uint4*)(seg + (size_t)blk * ELEMS_PER_BLOCK);
    #pragma unroll
    for (int j = 0; j < ELEMS_PER_BLOCK * 8 / 16 / 256; ++j)   // 16 iters
        g4[j * 256 + t] = s4[j * 256 + t];
}

__global__ __launch_bounds__(256) void p2_reduce(
    const uint2* __restrict__ seg, const uint32_t* __restrict__ table,
    float4* __restrict__ out4)
{
    __shared__ float acc[WORDS_PER_BIN];   // 64 KB output tile
    const int b = blockIdx.x, t = threadIdx.x;
    #pragma unroll
    for (int j = 0; j < WORDS_PER_BIN / 256; ++j) acc[t + j * 256] = 0.f;
    __syncthreads();

    #pragma unroll
    for (int ii = 0; ii < P1_BLOCKS / 256; ++ii) {
        const int i = t + ii * 256;                      // source p1 block
        const uint32_t s = table[(size_t)i * BINS + b];
        const uint32_t e = (b == BINS - 1) ? (uint32_t)ELEMS_PER_BLOCK
                                           : table[(size_t)i * BINS + b + 1];
        for (uint32_t k = s; k < e; ++k) {
            const uint2 en = seg[(size_t)i * ELEMS_PER_BLOCK + k];
            atomicAdd(&acc[en.x], __uint_as_float(en.y));  // ds_add_f32
        }
    }
    __syncthreads();

    const float4* a4 = (const float4*)acc;
    float4* o = out4 + (size_t)b * (WORDS_PER_BIN / 4);
    #pragma unroll
    for (int j = 0; j < WORDS_PER_BIN / 4 / 256; ++j)     // 16 iters
        o[j * 256 + t] = a4[j * 256 + t];
}

// ---------- fallback path (ws too small): zero + global atomics ----------
__global__ __launch_bounds__(256) void zero_out(float4* __restrict__ out)
{
    int t = blockIdx.x * blockDim.x + threadIdx.x;
    out[t] = float4{0.f, 0.f, 0.f, 0.f};
}

__global__ __launch_bounds__(256) void unpool_scatter(
    const float* __restrict__ in, const int* __restrict__ idx,
    float* __restrict__ out)
{
    int t = blockIdx.x * blockDim.x + threadIdx.x;
    float4 v  = reinterpret_cast<const float4*>(in)[t];
    int4   i4 = reinterpret_cast<const int4*>(idx)[t];
    int e0 = t << 2;
    int out_b = (e0 >> IN_PER_B_LOG2) << OUT_PER_B_LOG2;
    int c0 = e0 & 63;
    unsafeAtomicAdd(out + (out_b | (i4.x & ~63) | (c0 + 0)), v.x);
    unsafeAtomicAdd(out + (out_b | (i4.y & ~63) | (c0 + 1)), v.y);
    unsafeAtomicAdd(out + (out_b | (i4.z & ~63) | (c0 + 2)), v.z);
    unsafeAtomicAdd(out + (out_b | (i4.w & ~63) | (c0 + 3)), v.w);
}

extern "C" void kernel_launch(void* const* d_in, const int* in_sizes, int n_in,
                              void* d_out, int out_size, void* d_ws, size_t ws_size,
                              hipStream_t stream)
{
    const float* in  = (const float*)d_in[0];
    const int*   idx = (const int*)d_in[1];
    float*       out = (float*)d_out;
    const int threads = 256;

    if (ws_size >= WS_NEEDED) {
        uint2*    seg   = (uint2*)d_ws;
        uint32_t* table = (uint32_t*)((char*)d_ws + SEG_BYTES);
        p1_bin<<<P1_BLOCKS, threads, 0, stream>>>(
            (const float4*)in, (const int4*)idx, seg, table);
        p2_reduce<<<BINS, threads, 0, stream>>>(seg, table, (float4*)out);
    } else {
        zero_out<<<(out_size / 4) / threads, threads, 0, stream>>>((float4*)out);
        unpool_scatter<<<(int)(N / 4) / threads, threads, 0, stream>>>(in, idx, out);
    }
}